// Round 8
// baseline (323.577 us; speedup 1.0000x reference)
//
#include <hip/hip_runtime.h>

// ---------------------------------------------------------------------------
// GIN 3-layer: h_{l+1} = act((h + agg(h)) @ W + b)
// Restructured: z = act(h) @ W ; a = b + z + agg(z)   (agg commutes with W)
// SPLIT structure (measured best): oversubscribed gather kernels (latency-
// bound -> maximize waves in flight), bf16 z (halves gather bytes), fp32 a.
// GEMM = split-bf16 MFMA (hi*hi + hi*lo + lo*hi, fp32 acc), B pre-repacked.
// ---------------------------------------------------------------------------

typedef __attribute__((ext_vector_type(8))) short short8;
typedef __attribute__((ext_vector_type(4))) float f32x4;
typedef unsigned short ushort_t;
typedef unsigned int uint_t;

__device__ inline ushort_t bf16_rne(float f) {
  uint_t u = __float_as_uint(f);
  uint_t r = (u + 0x7FFFu + ((u >> 16) & 1u)) >> 16;
  return (ushort_t)r;
}
__device__ inline float bf16_to_f32(ushort_t h) {
  return __uint_as_float(((uint_t)h) << 16);
}

// ---- edge dtype detection: int64 (reference decl) vs int32 (JAX x64-off) ----
__global__ __launch_bounds__(256) void k_detect(const int* __restrict__ ew,
                                                int* __restrict__ flag, int E) {
  int i = blockIdx.x * 256 + threadIdx.x;
  int idx = 2 * i + 1;
  if (idx < 2 * E) {
    if (ew[idx] != 0) atomicOr(flag, 1);    // nonzero odd word => int32 layout
  }
}

// ---- CSR build --------------------------------------------------------------
__global__ __launch_bounds__(256) void k_hist(const void* __restrict__ edges,
                                              const int* __restrict__ flag,
                                              int* __restrict__ counts, int E) {
  int e = blockIdx.x * 256 + threadIdx.x;
  if (e >= E) return;
  int d;
  if (*flag) d = ((const int*)edges)[E + e];
  else       d = (int)((const long long*)edges)[E + e];
  atomicAdd(&counts[d], 1);   // 100k distinct counters -> low contention
}

__global__ __launch_bounds__(256) void k_scan1(const int* __restrict__ counts,
                                               int* __restrict__ offs,
                                               int* __restrict__ bsum, int N) {
  __shared__ int s[256];
  int t = threadIdx.x;
  int base = blockIdx.x * 1024 + t * 4;
  int c0 = 0, c1 = 0, c2 = 0, c3 = 0;
  if (base + 0 < N) c0 = counts[base + 0];
  if (base + 1 < N) c1 = counts[base + 1];
  if (base + 2 < N) c2 = counts[base + 2];
  if (base + 3 < N) c3 = counts[base + 3];
  int mySum = c0 + c1 + c2 + c3;
  s[t] = mySum;
  __syncthreads();
  for (int d = 1; d < 256; d <<= 1) {
    int v = (t >= d) ? s[t - d] : 0;
    __syncthreads();
    s[t] += v;
    __syncthreads();
  }
  int excl = s[t] - mySum;
  if (base + 0 < N) offs[base + 0] = excl;
  if (base + 1 < N) offs[base + 1] = excl + c0;
  if (base + 2 < N) offs[base + 2] = excl + c0 + c1;
  if (base + 3 < N) offs[base + 3] = excl + c0 + c1 + c2;
  if (t == 255) bsum[blockIdx.x] = s[255];
}

__global__ __launch_bounds__(128) void k_scan2(int* __restrict__ bsum, int nb) {
  __shared__ int s[128];
  int t = threadIdx.x;
  int v = (t < nb) ? bsum[t] : 0;
  s[t] = v;
  __syncthreads();
  for (int d = 1; d < 128; d <<= 1) {
    int u = (t >= d) ? s[t - d] : 0;
    __syncthreads();
    s[t] += u;
    __syncthreads();
  }
  if (t < nb) bsum[t] = s[t] - v;
}

__global__ __launch_bounds__(256) void k_scan3(int* __restrict__ offs,
                                               const int* __restrict__ bsum,
                                               int* __restrict__ cursor,
                                               int N, int E) {
  int t = threadIdx.x;
  int add = bsum[blockIdx.x];
  int base = blockIdx.x * 1024 + t * 4;
#pragma unroll
  for (int j = 0; j < 4; j++) {
    int i = base + j;
    if (i < N) { int v = offs[i] + add; offs[i] = v; cursor[i] = v; }
  }
  if (blockIdx.x == 0 && t == 0) offs[N] = E;
}

__global__ __launch_bounds__(256) void k_fill(const void* __restrict__ edges,
                                              const int* __restrict__ flag,
                                              int* __restrict__ cursor,
                                              int* __restrict__ csr, int E) {
  int e = blockIdx.x * 256 + threadIdx.x;
  if (e >= E) return;
  int s, d;
  if (*flag) {
    const int* p = (const int*)edges;
    s = p[e]; d = p[E + e];
  } else {
    const long long* p = (const long long*)edges;
    s = (int)p[e]; d = (int)p[E + e];
  }
  int pos = atomicAdd(&cursor[d], 1);
  csr[pos] = s;
}

// ---- W repack into MFMA B-fragment order (hi/lo split bf16) -----------------
__global__ __launch_bounds__(256) void k_repack(
    const float* __restrict__ W1, const float* __restrict__ W2,
    const float* __restrict__ W3,
    ushort_t* __restrict__ h1, ushort_t* __restrict__ l1,
    ushort_t* __restrict__ h2, ushort_t* __restrict__ l2,
    ushort_t* __restrict__ h3, ushort_t* __restrict__ l3) {
  int idx = blockIdx.x * 256 + threadIdx.x;
  const float* W; ushort_t* H; ushort_t* L; int NC; int i;
  if (idx < 16384)      { W = W1; H = h1; L = l1; NC = 128; i = idx; }
  else if (idx < 32768) { W = W2; H = h2; L = l2; NC = 128; i = idx - 16384; }
  else if (idx < 40960) { W = W3; H = h3; L = l3; NC = 64;  i = idx - 32768; }
  else return;
  int j = i & 7;
  int lane = (i >> 3) & 63;
  int NT = NC >> 4;
  int tile = (i >> 9) & (NT - 1);
  int ks = i >> (9 + (NC == 128 ? 3 : 2));
  int k = ks * 32 + (lane >> 4) * 8 + j;
  int n = tile * 16 + (lane & 15);
  float v = W[(size_t)k * NC + n];
  ushort_t hi = bf16_rne(v);
  ushort_t lo = bf16_rne(v - bf16_to_f32(hi));
  H[i] = hi; L[i] = lo;
}

// ---- GEMM: Z(bf16)[M x NC] = act(A(fp32)[M x 128]) @ W ----------------------
template <int NC, bool RELU>
__global__ __launch_bounds__(256) void k_gemm_mfma(
    const float* __restrict__ A, const ushort_t* __restrict__ Bhi,
    const ushort_t* __restrict__ Blo, ushort_t* __restrict__ Z, int M) {
  constexpr int NT = NC / 16;
  int lane = threadIdx.x & 63;
  int wave = threadIdx.x >> 6;
  int row0 = blockIdx.x * 64 + wave * 16;
  int m = lane & 15;
  int q = lane >> 4;
  int grow = row0 + m;
  bool rowok = (grow < M);

  f32x4 acc[NT];
#pragma unroll
  for (int t = 0; t < NT; t++) { acc[t][0] = 0.f; acc[t][1] = 0.f; acc[t][2] = 0.f; acc[t][3] = 0.f; }

  const float* arow = A + (size_t)(rowok ? grow : 0) * 128 + q * 8;

#pragma unroll
  for (int ks = 0; ks < 4; ks++) {
    float av[8];
    *(float4*)(av)     = *(const float4*)(arow + ks * 32);
    *(float4*)(av + 4) = *(const float4*)(arow + ks * 32 + 4);
    short8 ahi, alo;
#pragma unroll
    for (int j = 0; j < 8; j++) {
      float v = RELU ? fmaxf(av[j], 0.f) : av[j];
      ushort_t hi = bf16_rne(v);
      ahi[j] = (short)hi;
      alo[j] = (short)bf16_rne(v - bf16_to_f32(hi));
    }
#pragma unroll
    for (int t = 0; t < NT; t++) {
      const short8 bh = *(const short8*)(Bhi + (((size_t)ks * NT + t) * 64 + lane) * 8);
      const short8 bl = *(const short8*)(Blo + (((size_t)ks * NT + t) * 64 + lane) * 8);
      acc[t] = __builtin_amdgcn_mfma_f32_16x16x32_bf16(ahi, bh, acc[t], 0, 0, 0);
      acc[t] = __builtin_amdgcn_mfma_f32_16x16x32_bf16(ahi, bl, acc[t], 0, 0, 0);
      acc[t] = __builtin_amdgcn_mfma_f32_16x16x32_bf16(alo, bh, acc[t], 0, 0, 0);
    }
  }

  int zrow = row0 + q * 4;
#pragma unroll
  for (int r = 0; r < 4; r++) {
    if (zrow + r < M) {
#pragma unroll
      for (int t = 0; t < NT; t++)
        Z[(size_t)(zrow + r) * NC + t * 16 + m] = bf16_rne(acc[t][r]);
    }
  }
}

// ---- agg (128 cols): a(fp32) = bias + z + agg(z), z bf16 --------------------
// 16 lanes per node (8 bf16 cols each, b128 loads), 16 nodes/block -> 6250
// blocks = 25k waves: oversubscription keeps ~32 waves/CU refilled (the
// gather is latency-bound; concurrency is the lever). Unroll x4.
__global__ __launch_bounds__(256) void k_agg128(const ushort_t* __restrict__ z,
                                                const int* __restrict__ csr,
                                                const int* __restrict__ offs,
                                                const float* __restrict__ bias,
                                                float* __restrict__ a, int N) {
  int t = threadIdx.x;
  int node = blockIdx.x * 16 + (t >> 4);
  if (node >= N) return;
  int c = (t & 15) * 8;
  float acc[8];
  {
    short8 u = *(const short8*)(z + (size_t)node * 128 + c);
#pragma unroll
    for (int jj = 0; jj < 8; jj++)
      acc[jj] = bias[c + jj] + bf16_to_f32((ushort_t)u[jj]);
  }
  int s = offs[node], e = offs[node + 1];
  int j = s;
  for (; j + 4 <= e; j += 4) {
    int i0 = csr[j], i1 = csr[j + 1], i2 = csr[j + 2], i3 = csr[j + 3];
    short8 u0 = *(const short8*)(z + (size_t)i0 * 128 + c);
    short8 u1 = *(const short8*)(z + (size_t)i1 * 128 + c);
    short8 u2 = *(const short8*)(z + (size_t)i2 * 128 + c);
    short8 u3 = *(const short8*)(z + (size_t)i3 * 128 + c);
#pragma unroll
    for (int jj = 0; jj < 8; jj++)
      acc[jj] += (bf16_to_f32((ushort_t)u0[jj]) + bf16_to_f32((ushort_t)u1[jj])) +
                 (bf16_to_f32((ushort_t)u2[jj]) + bf16_to_f32((ushort_t)u3[jj]));
  }
  for (; j < e; j++) {
    int i0 = csr[j];
    short8 u = *(const short8*)(z + (size_t)i0 * 128 + c);
#pragma unroll
    for (int jj = 0; jj < 8; jj++)
      acc[jj] += bf16_to_f32((ushort_t)u[jj]);
  }
  float4 o0 = make_float4(acc[0], acc[1], acc[2], acc[3]);
  float4 o1 = make_float4(acc[4], acc[5], acc[6], acc[7]);
  *(float4*)&a[(size_t)node * 128 + c]     = o0;
  *(float4*)&a[(size_t)node * 128 + c + 4] = o1;
}

// ---- final agg (64 cols): out(fp32) = bias + z + agg(z), z bf16 -------------
// 8 lanes per node, 32 nodes/block -> 3125 blocks. Unroll x4.
__global__ __launch_bounds__(256) void k_agg64(const ushort_t* __restrict__ z,
                                               const int* __restrict__ csr,
                                               const int* __restrict__ offs,
                                               const float* __restrict__ bias,
                                               float* __restrict__ out, int N) {
  int t = threadIdx.x;
  int node = blockIdx.x * 32 + (t >> 3);
  if (node >= N) return;
  int c = (t & 7) * 8;
  float acc[8];
  {
    short8 u = *(const short8*)(z + (size_t)node * 64 + c);
#pragma unroll
    for (int jj = 0; jj < 8; jj++)
      acc[jj] = bias[c + jj] + bf16_to_f32((ushort_t)u[jj]);
  }
  int s = offs[node], e = offs[node + 1];
  int j = s;
  for (; j + 4 <= e; j += 4) {
    int i0 = csr[j], i1 = csr[j + 1], i2 = csr[j + 2], i3 = csr[j + 3];
    short8 u0 = *(const short8*)(z + (size_t)i0 * 64 + c);
    short8 u1 = *(const short8*)(z + (size_t)i1 * 64 + c);
    short8 u2 = *(const short8*)(z + (size_t)i2 * 64 + c);
    short8 u3 = *(const short8*)(z + (size_t)i3 * 64 + c);
#pragma unroll
    for (int jj = 0; jj < 8; jj++)
      acc[jj] += (bf16_to_f32((ushort_t)u0[jj]) + bf16_to_f32((ushort_t)u1[jj])) +
                 (bf16_to_f32((ushort_t)u2[jj]) + bf16_to_f32((ushort_t)u3[jj]));
  }
  for (; j < e; j++) {
    int i0 = csr[j];
    short8 u = *(const short8*)(z + (size_t)i0 * 64 + c);
#pragma unroll
    for (int jj = 0; jj < 8; jj++)
      acc[jj] += bf16_to_f32((ushort_t)u[jj]);
  }
  float4 o0 = make_float4(acc[0], acc[1], acc[2], acc[3]);
  float4 o1 = make_float4(acc[4], acc[5], acc[6], acc[7]);
  *(float4*)&out[(size_t)node * 64 + c]     = o0;
  *(float4*)&out[(size_t)node * 64 + c + 4] = o1;
}

// ---------------------------------------------------------------------------
extern "C" void kernel_launch(void* const* d_in, const int* in_sizes, int n_in,
                              void* d_out, int out_size, void* d_ws, size_t ws_size,
                              hipStream_t stream) {
  const float* x  = (const float*)d_in[0];
  const void* edges = d_in[1];
  const float* W1 = (const float*)d_in[2];
  const float* b1 = (const float*)d_in[3];
  const float* W2 = (const float*)d_in[4];
  const float* b2 = (const float*)d_in[5];
  const float* W3 = (const float*)d_in[6];
  const float* b3 = (const float*)d_in[7];
  float* out = (float*)d_out;

  int N = in_sizes[0] / 128;   // 100000
  int E = in_sizes[1] / 2;     // 600000

  char* w = (char*)d_ws;
  size_t off = 0;
  auto alloc = [&](size_t bytes) -> void* {
    void* p = w + off;
    off = (off + bytes + 255) & ~(size_t)255;
    return p;
  };
  size_t curBytes = ((size_t)N * 4 + 255) & ~(size_t)255;
  int*   cursor = (int*)alloc(curBytes);     // degree counts, then fill cursor
  int*   flag   = (int*)alloc(4);            // adjacent: one memset covers both
  int*   csr    = (int*)alloc((size_t)E * 4);
  int*   offs   = (int*)alloc((size_t)(N + 1) * 4);
  int*   bsum   = (int*)alloc(4096);
  ushort_t* h1  = (ushort_t*)alloc(16384 * 2);
  ushort_t* l1  = (ushort_t*)alloc(16384 * 2);
  ushort_t* h2  = (ushort_t*)alloc(16384 * 2);
  ushort_t* l2  = (ushort_t*)alloc(16384 * 2);
  ushort_t* h3  = (ushort_t*)alloc(8192 * 2);
  ushort_t* l3  = (ushort_t*)alloc(8192 * 2);
  ushort_t* z   = (ushort_t*)alloc((size_t)N * 128 * 2);  // bf16, reused /layer
  float*    a   = (float*)alloc((size_t)N * 128 * 4);     // fp32, reused /layer

  int ge = (E + 255) / 256;
  int nb = (N + 1023) / 1024;

  hipMemsetAsync(cursor, 0, curBytes + 4, stream);
  k_detect<<<4, 256, 0, stream>>>((const int*)edges, flag, E);
  k_hist<<<ge, 256, 0, stream>>>(edges, flag, cursor, E);
  k_scan1<<<nb, 256, 0, stream>>>(cursor, offs, bsum, N);
  k_scan2<<<1, 128, 0, stream>>>(bsum, nb);
  k_scan3<<<nb, 256, 0, stream>>>(offs, bsum, cursor, N, E);
  k_fill<<<ge, 256, 0, stream>>>(edges, flag, cursor, csr, E);
  k_repack<<<160, 256, 0, stream>>>(W1, W2, W3, h1, l1, h2, l2, h3, l3);

  int gm = (N + 63) / 64;
  // layer 1: z = x @ W1 ; a = b1 + z + agg(z)
  k_gemm_mfma<128, false><<<gm, 256, 0, stream>>>(x, h1, l1, z, N);
  k_agg128<<<(N + 15) / 16, 256, 0, stream>>>(z, csr, offs, b1, a, N);
  // layer 2: z = relu(a) @ W2 ; a = b2 + z + agg(z)
  k_gemm_mfma<128, true><<<gm, 256, 0, stream>>>(a, h2, l2, z, N);
  k_agg128<<<(N + 15) / 16, 256, 0, stream>>>(z, csr, offs, b2, a, N);
  // layer 3: z = relu(a) @ W3 ; out = b3 + z + agg(z)
  k_gemm_mfma<64, true><<<gm, 256, 0, stream>>>(a, h3, l3, z, N);
  k_agg64<<<(N + 31) / 32, 256, 0, stream>>>(z, csr, offs, b3, out, N);
}

// Round 9
// 301.079 us; speedup vs baseline: 1.0747x; 1.0747x over previous
//
#include <hip/hip_runtime.h>

// ---------------------------------------------------------------------------
// GIN 3-layer: h_{l+1} = act((h + agg(h)) @ W + b)
// Restructured: z = act(h) @ W ; a = relu(b + z + agg(z))  (agg commutes w/ W)
// z AND a stored BF16 (a has relu fused -> GEMM A-operand is raw bf16
// fragment, 2 MFMAs/tile, no repack). Aggs: clamp+weight unroll-4 loop
// (no serial remainder). Split structure (oversubscribed latency-bound aggs).
// ---------------------------------------------------------------------------

typedef __attribute__((ext_vector_type(8))) short short8;
typedef __attribute__((ext_vector_type(4))) float f32x4;
typedef unsigned short ushort_t;
typedef unsigned int uint_t;

__device__ inline ushort_t bf16_rne(float f) {
  uint_t u = __float_as_uint(f);
  uint_t r = (u + 0x7FFFu + ((u >> 16) & 1u)) >> 16;
  return (ushort_t)r;
}
__device__ inline float bf16_to_f32(ushort_t h) {
  return __uint_as_float(((uint_t)h) << 16);
}

// ---- edge dtype detection: int64 (reference decl) vs int32 (JAX x64-off) ----
__global__ __launch_bounds__(256) void k_detect(const int* __restrict__ ew,
                                                int* __restrict__ flag, int E) {
  int i = blockIdx.x * 256 + threadIdx.x;
  int idx = 2 * i + 1;
  if (idx < 2 * E) {
    if (ew[idx] != 0) atomicOr(flag, 1);    // nonzero odd word => int32 layout
  }
}

// ---- CSR build --------------------------------------------------------------
__global__ __launch_bounds__(256) void k_hist(const void* __restrict__ edges,
                                              const int* __restrict__ flag,
                                              int* __restrict__ counts, int E) {
  int e = blockIdx.x * 256 + threadIdx.x;
  if (e >= E) return;
  int d;
  if (*flag) d = ((const int*)edges)[E + e];
  else       d = (int)((const long long*)edges)[E + e];
  atomicAdd(&counts[d], 1);   // 100k distinct counters -> low contention
}

__global__ __launch_bounds__(256) void k_scan1(const int* __restrict__ counts,
                                               int* __restrict__ offs,
                                               int* __restrict__ bsum, int N) {
  __shared__ int s[256];
  int t = threadIdx.x;
  int base = blockIdx.x * 1024 + t * 4;
  int c0 = 0, c1 = 0, c2 = 0, c3 = 0;
  if (base + 0 < N) c0 = counts[base + 0];
  if (base + 1 < N) c1 = counts[base + 1];
  if (base + 2 < N) c2 = counts[base + 2];
  if (base + 3 < N) c3 = counts[base + 3];
  int mySum = c0 + c1 + c2 + c3;
  s[t] = mySum;
  __syncthreads();
  for (int d = 1; d < 256; d <<= 1) {
    int v = (t >= d) ? s[t - d] : 0;
    __syncthreads();
    s[t] += v;
    __syncthreads();
  }
  int excl = s[t] - mySum;
  if (base + 0 < N) offs[base + 0] = excl;
  if (base + 1 < N) offs[base + 1] = excl + c0;
  if (base + 2 < N) offs[base + 2] = excl + c0 + c1;
  if (base + 3 < N) offs[base + 3] = excl + c0 + c1 + c2;
  if (t == 255) bsum[blockIdx.x] = s[255];
}

__global__ __launch_bounds__(128) void k_scan2(int* __restrict__ bsum, int nb) {
  __shared__ int s[128];
  int t = threadIdx.x;
  int v = (t < nb) ? bsum[t] : 0;
  s[t] = v;
  __syncthreads();
  for (int d = 1; d < 128; d <<= 1) {
    int u = (t >= d) ? s[t - d] : 0;
    __syncthreads();
    s[t] += u;
    __syncthreads();
  }
  if (t < nb) bsum[t] = s[t] - v;
}

__global__ __launch_bounds__(256) void k_scan3(int* __restrict__ offs,
                                               const int* __restrict__ bsum,
                                               int* __restrict__ cursor,
                                               int N, int E) {
  int t = threadIdx.x;
  int add = bsum[blockIdx.x];
  int base = blockIdx.x * 1024 + t * 4;
#pragma unroll
  for (int j = 0; j < 4; j++) {
    int i = base + j;
    if (i < N) { int v = offs[i] + add; offs[i] = v; cursor[i] = v; }
  }
  if (blockIdx.x == 0 && t == 0) offs[N] = E;
}

__global__ __launch_bounds__(256) void k_fill(const void* __restrict__ edges,
                                              const int* __restrict__ flag,
                                              int* __restrict__ cursor,
                                              int* __restrict__ csr, int E) {
  int e = blockIdx.x * 256 + threadIdx.x;
  if (e >= E) return;
  int s, d;
  if (*flag) {
    const int* p = (const int*)edges;
    s = p[e]; d = p[E + e];
  } else {
    const long long* p = (const long long*)edges;
    s = (int)p[e]; d = (int)p[E + e];
  }
  int pos = atomicAdd(&cursor[d], 1);
  csr[pos] = s;
}

// ---- W repack into MFMA B-fragment order (hi/lo split bf16) -----------------
__global__ __launch_bounds__(256) void k_repack(
    const float* __restrict__ W1, const float* __restrict__ W2,
    const float* __restrict__ W3,
    ushort_t* __restrict__ h1, ushort_t* __restrict__ l1,
    ushort_t* __restrict__ h2, ushort_t* __restrict__ l2,
    ushort_t* __restrict__ h3, ushort_t* __restrict__ l3) {
  int idx = blockIdx.x * 256 + threadIdx.x;
  const float* W; ushort_t* H; ushort_t* L; int NC; int i;
  if (idx < 16384)      { W = W1; H = h1; L = l1; NC = 128; i = idx; }
  else if (idx < 32768) { W = W2; H = h2; L = l2; NC = 128; i = idx - 16384; }
  else if (idx < 40960) { W = W3; H = h3; L = l3; NC = 64;  i = idx - 32768; }
  else return;
  int j = i & 7;
  int lane = (i >> 3) & 63;
  int NT = NC >> 4;
  int tile = (i >> 9) & (NT - 1);
  int ks = i >> (9 + (NC == 128 ? 3 : 2));
  int k = ks * 32 + (lane >> 4) * 8 + j;
  int n = tile * 16 + (lane & 15);
  float v = W[(size_t)k * NC + n];
  ushort_t hi = bf16_rne(v);
  ushort_t lo = bf16_rne(v - bf16_to_f32(hi));
  H[i] = hi; L[i] = lo;
}

// ---- layer-1 GEMM: Z(bf16) = A(fp32)[M x 128] @ W  (split hi/lo A) ----------
__global__ __launch_bounds__(256) void k_gemm_l1(
    const float* __restrict__ A, const ushort_t* __restrict__ Bhi,
    const ushort_t* __restrict__ Blo, ushort_t* __restrict__ Z, int M) {
  constexpr int NC = 128, NT = 8;
  int lane = threadIdx.x & 63;
  int wave = threadIdx.x >> 6;
  int row0 = blockIdx.x * 64 + wave * 16;
  int m = lane & 15;
  int q = lane >> 4;
  int grow = row0 + m;
  bool rowok = (grow < M);

  f32x4 acc[NT];
#pragma unroll
  for (int t = 0; t < NT; t++) { acc[t][0] = 0.f; acc[t][1] = 0.f; acc[t][2] = 0.f; acc[t][3] = 0.f; }

  const float* arow = A + (size_t)(rowok ? grow : 0) * 128 + q * 8;

#pragma unroll
  for (int ks = 0; ks < 4; ks++) {
    float av[8];
    *(float4*)(av)     = *(const float4*)(arow + ks * 32);
    *(float4*)(av + 4) = *(const float4*)(arow + ks * 32 + 4);
    short8 ahi, alo;
#pragma unroll
    for (int j = 0; j < 8; j++) {
      ushort_t hi = bf16_rne(av[j]);
      ahi[j] = (short)hi;
      alo[j] = (short)bf16_rne(av[j] - bf16_to_f32(hi));
    }
#pragma unroll
    for (int t = 0; t < NT; t++) {
      const short8 bh = *(const short8*)(Bhi + (((size_t)ks * NT + t) * 64 + lane) * 8);
      const short8 bl = *(const short8*)(Blo + (((size_t)ks * NT + t) * 64 + lane) * 8);
      acc[t] = __builtin_amdgcn_mfma_f32_16x16x32_bf16(ahi, bh, acc[t], 0, 0, 0);
      acc[t] = __builtin_amdgcn_mfma_f32_16x16x32_bf16(ahi, bl, acc[t], 0, 0, 0);
      acc[t] = __builtin_amdgcn_mfma_f32_16x16x32_bf16(alo, bh, acc[t], 0, 0, 0);
    }
  }

  int zrow = row0 + q * 4;
#pragma unroll
  for (int r = 0; r < 4; r++) {
    if (zrow + r < M) {
#pragma unroll
      for (int t = 0; t < NT; t++)
        Z[(size_t)(zrow + r) * NC + t * 16 + m] = bf16_rne(acc[t][r]);
    }
  }
}

// ---- layer-2/3 GEMM: Z(bf16) = A(bf16, pre-relu'd) @ W  (2 MFMAs/tile) ------
// A rows ARE the MFMA bf16 A-fragment: zero repack VALU in the K-loop.
template <int NC>
__global__ __launch_bounds__(256) void k_gemm_bf(
    const ushort_t* __restrict__ A, const ushort_t* __restrict__ Bhi,
    const ushort_t* __restrict__ Blo, ushort_t* __restrict__ Z, int M) {
  constexpr int NT = NC / 16;
  int lane = threadIdx.x & 63;
  int wave = threadIdx.x >> 6;
  int row0 = blockIdx.x * 64 + wave * 16;
  int m = lane & 15;
  int q = lane >> 4;
  int grow = row0 + m;
  bool rowok = (grow < M);

  f32x4 acc[NT];
#pragma unroll
  for (int t = 0; t < NT; t++) { acc[t][0] = 0.f; acc[t][1] = 0.f; acc[t][2] = 0.f; acc[t][3] = 0.f; }

  const ushort_t* arow = A + (size_t)(rowok ? grow : 0) * 128 + q * 8;

#pragma unroll
  for (int ks = 0; ks < 4; ks++) {
    short8 a8 = *(const short8*)(arow + ks * 32);
#pragma unroll
    for (int t = 0; t < NT; t++) {
      const short8 bh = *(const short8*)(Bhi + (((size_t)ks * NT + t) * 64 + lane) * 8);
      const short8 bl = *(const short8*)(Blo + (((size_t)ks * NT + t) * 64 + lane) * 8);
      acc[t] = __builtin_amdgcn_mfma_f32_16x16x32_bf16(a8, bh, acc[t], 0, 0, 0);
      acc[t] = __builtin_amdgcn_mfma_f32_16x16x32_bf16(a8, bl, acc[t], 0, 0, 0);
    }
  }

  int zrow = row0 + q * 4;
#pragma unroll
  for (int r = 0; r < 4; r++) {
    if (zrow + r < M) {
#pragma unroll
      for (int t = 0; t < NT; t++)
        Z[(size_t)(zrow + r) * NC + t * 16 + m] = bf16_rne(acc[t][r]);
    }
  }
}

// ---- agg (128 cols): a(bf16) = relu(bias + z + agg(z)), z bf16 --------------
// 16 lanes/node (16B each), 16 nodes/block -> 25k waves (oversubscribe; the
// gather is latency-bound). Clamp+weight unroll-4: no serial remainder.
__global__ __launch_bounds__(256) void k_agg128(const ushort_t* __restrict__ z,
                                                const int* __restrict__ csr,
                                                const int* __restrict__ offs,
                                                const float* __restrict__ bias,
                                                ushort_t* __restrict__ a, int N) {
  int t = threadIdx.x;
  int node = blockIdx.x * 16 + (t >> 4);
  if (node >= N) return;
  int c = (t & 15) * 8;
  float acc[8];
  {
    short8 u = *(const short8*)(z + (size_t)node * 128 + c);
#pragma unroll
    for (int jj = 0; jj < 8; jj++)
      acc[jj] = bias[c + jj] + bf16_to_f32((ushort_t)u[jj]);
  }
  int s = offs[node], e = offs[node + 1];
  for (int j = s; j < e; j += 4) {
    int j1 = min(j + 1, e - 1), j2 = min(j + 2, e - 1), j3 = min(j + 3, e - 1);
    int i0 = csr[j], i1 = csr[j1], i2 = csr[j2], i3 = csr[j3];
    float w1 = (j + 1 < e) ? 1.f : 0.f;
    float w2 = (j + 2 < e) ? 1.f : 0.f;
    float w3 = (j + 3 < e) ? 1.f : 0.f;
    short8 u0 = *(const short8*)(z + (size_t)i0 * 128 + c);
    short8 u1 = *(const short8*)(z + (size_t)i1 * 128 + c);
    short8 u2 = *(const short8*)(z + (size_t)i2 * 128 + c);
    short8 u3 = *(const short8*)(z + (size_t)i3 * 128 + c);
#pragma unroll
    for (int jj = 0; jj < 8; jj++) {
      float v = acc[jj] + bf16_to_f32((ushort_t)u0[jj]);
      v = fmaf(w1, bf16_to_f32((ushort_t)u1[jj]), v);
      v = fmaf(w2, bf16_to_f32((ushort_t)u2[jj]), v);
      v = fmaf(w3, bf16_to_f32((ushort_t)u3[jj]), v);
      acc[jj] = v;
    }
  }
  short8 o;
#pragma unroll
  for (int jj = 0; jj < 8; jj++)
    o[jj] = (short)bf16_rne(fmaxf(acc[jj], 0.f));   // relu fused
  *(short8*)(a + (size_t)node * 128 + c) = o;
}

// ---- final agg (64 cols): out(fp32) = bias + z + agg(z), z bf16 -------------
__global__ __launch_bounds__(256) void k_agg64(const ushort_t* __restrict__ z,
                                               const int* __restrict__ csr,
                                               const int* __restrict__ offs,
                                               const float* __restrict__ bias,
                                               float* __restrict__ out, int N) {
  int t = threadIdx.x;
  int node = blockIdx.x * 32 + (t >> 3);
  if (node >= N) return;
  int c = (t & 7) * 8;
  float acc[8];
  {
    short8 u = *(const short8*)(z + (size_t)node * 64 + c);
#pragma unroll
    for (int jj = 0; jj < 8; jj++)
      acc[jj] = bias[c + jj] + bf16_to_f32((ushort_t)u[jj]);
  }
  int s = offs[node], e = offs[node + 1];
  for (int j = s; j < e; j += 4) {
    int j1 = min(j + 1, e - 1), j2 = min(j + 2, e - 1), j3 = min(j + 3, e - 1);
    int i0 = csr[j], i1 = csr[j1], i2 = csr[j2], i3 = csr[j3];
    float w1 = (j + 1 < e) ? 1.f : 0.f;
    float w2 = (j + 2 < e) ? 1.f : 0.f;
    float w3 = (j + 3 < e) ? 1.f : 0.f;
    short8 u0 = *(const short8*)(z + (size_t)i0 * 64 + c);
    short8 u1 = *(const short8*)(z + (size_t)i1 * 64 + c);
    short8 u2 = *(const short8*)(z + (size_t)i2 * 64 + c);
    short8 u3 = *(const short8*)(z + (size_t)i3 * 64 + c);
#pragma unroll
    for (int jj = 0; jj < 8; jj++) {
      float v = acc[jj] + bf16_to_f32((ushort_t)u0[jj]);
      v = fmaf(w1, bf16_to_f32((ushort_t)u1[jj]), v);
      v = fmaf(w2, bf16_to_f32((ushort_t)u2[jj]), v);
      v = fmaf(w3, bf16_to_f32((ushort_t)u3[jj]), v);
      acc[jj] = v;
    }
  }
  float4 o0 = make_float4(acc[0], acc[1], acc[2], acc[3]);
  float4 o1 = make_float4(acc[4], acc[5], acc[6], acc[7]);
  *(float4*)&out[(size_t)node * 64 + c]     = o0;
  *(float4*)&out[(size_t)node * 64 + c + 4] = o1;
}

// ---------------------------------------------------------------------------
extern "C" void kernel_launch(void* const* d_in, const int* in_sizes, int n_in,
                              void* d_out, int out_size, void* d_ws, size_t ws_size,
                              hipStream_t stream) {
  const float* x  = (const float*)d_in[0];
  const void* edges = d_in[1];
  const float* W1 = (const float*)d_in[2];
  const float* b1 = (const float*)d_in[3];
  const float* W2 = (const float*)d_in[4];
  const float* b2 = (const float*)d_in[5];
  const float* W3 = (const float*)d_in[6];
  const float* b3 = (const float*)d_in[7];
  float* out = (float*)d_out;

  int N = in_sizes[0] / 128;   // 100000
  int E = in_sizes[1] / 2;     // 600000

  char* w = (char*)d_ws;
  size_t off = 0;
  auto alloc = [&](size_t bytes) -> void* {
    void* p = w + off;
    off = (off + bytes + 255) & ~(size_t)255;
    return p;
  };
  size_t curBytes = ((size_t)N * 4 + 255) & ~(size_t)255;
  int*   cursor = (int*)alloc(curBytes);     // degree counts, then fill cursor
  int*   flag   = (int*)alloc(4);            // adjacent: one memset covers both
  int*   csr    = (int*)alloc((size_t)E * 4);
  int*   offs   = (int*)alloc((size_t)(N + 1) * 4);
  int*   bsum   = (int*)alloc(4096);
  ushort_t* h1  = (ushort_t*)alloc(16384 * 2);
  ushort_t* l1  = (ushort_t*)alloc(16384 * 2);
  ushort_t* h2  = (ushort_t*)alloc(16384 * 2);
  ushort_t* l2  = (ushort_t*)alloc(16384 * 2);
  ushort_t* h3  = (ushort_t*)alloc(8192 * 2);
  ushort_t* l3  = (ushort_t*)alloc(8192 * 2);
  ushort_t* z   = (ushort_t*)alloc((size_t)N * 128 * 2);  // bf16, reused /layer
  ushort_t* a   = (ushort_t*)alloc((size_t)N * 128 * 2);  // bf16 relu'd, reused

  int ge = (E + 255) / 256;
  int nb = (N + 1023) / 1024;

  hipMemsetAsync(cursor, 0, curBytes + 4, stream);
  k_detect<<<4, 256, 0, stream>>>((const int*)edges, flag, E);
  k_hist<<<ge, 256, 0, stream>>>(edges, flag, cursor, E);
  k_scan1<<<nb, 256, 0, stream>>>(cursor, offs, bsum, N);
  k_scan2<<<1, 128, 0, stream>>>(bsum, nb);
  k_scan3<<<nb, 256, 0, stream>>>(offs, bsum, cursor, N, E);
  k_fill<<<ge, 256, 0, stream>>>(edges, flag, cursor, csr, E);
  k_repack<<<160, 256, 0, stream>>>(W1, W2, W3, h1, l1, h2, l2, h3, l3);

  int gm = (N + 63) / 64;
  // layer 1: z = x @ W1 ; a = relu(b1 + z + agg(z))  [bf16]
  k_gemm_l1<<<gm, 256, 0, stream>>>(x, h1, l1, z, N);
  k_agg128<<<(N + 15) / 16, 256, 0, stream>>>(z, csr, offs, b1, a, N);
  // layer 2: z = a @ W2 ; a = relu(b2 + z + agg(z))  [bf16]
  k_gemm_bf<128><<<gm, 256, 0, stream>>>(a, h2, l2, z, N);
  k_agg128<<<(N + 15) / 16, 256, 0, stream>>>(z, csr, offs, b2, a, N);
  // layer 3: z = a @ W3 ; out = b3 + z + agg(z)  [fp32 out]
  k_gemm_bf<64><<<gm, 256, 0, stream>>>(a, h3, l3, z, N);
  k_agg64<<<(N + 31) / 32, 256, 0, stream>>>(z, csr, offs, b3, out, N);
}